// Round 1
// baseline (273.722 us; speedup 1.0000x reference)
//
#include <hip/hip_runtime.h>

// ArcFace loss, MI355X. B=512, D=512, C=64000, s=64, m=0.5.
// Pipeline: normalize x,W -> bf16; MFMA GEMM (theta) with fused
// exp-sum epilogue (no theta materialization); tiny finalize kernel.

#define B_N 512
#define D_N 512
#define C_N 64000
#define S_SCALE 64.0f
#define MARGIN 0.5f
#define EPS_C 1e-7f

typedef unsigned short ushort_t;
typedef __attribute__((ext_vector_type(8))) short short8;   // 8 bf16 (4 VGPRs)
typedef __attribute__((ext_vector_type(4))) float floatx4;  // MFMA acc

__device__ __forceinline__ ushort_t f2bf(float f) {
    unsigned int u = __float_as_uint(f);
    u += 0x7fffu + ((u >> 16) & 1u);  // round-to-nearest-even
    return (ushort_t)(u >> 16);
}

// One wave per row: load 512 floats (8/lane as 2x float4), L2-norm via
// shuffle butterfly, write 8 bf16/lane as one uint4 (16B store).
__global__ void norm_rows_kernel(const float* __restrict__ src,
                                 ushort_t* __restrict__ dst, int nrows) {
    int row  = blockIdx.x * 4 + (threadIdx.x >> 6);
    int lane = threadIdx.x & 63;
    if (row >= nrows) return;
    const float4* p = (const float4*)(src + (size_t)row * D_N);
    float4 v0 = p[lane * 2];
    float4 v1 = p[lane * 2 + 1];
    float ss = v0.x*v0.x + v0.y*v0.y + v0.z*v0.z + v0.w*v0.w
             + v1.x*v1.x + v1.y*v1.y + v1.z*v1.z + v1.w*v1.w;
#pragma unroll
    for (int off = 32; off > 0; off >>= 1) ss += __shfl_xor(ss, off);
    float scale = 1.0f / fmaxf(sqrtf(ss), 1e-12f);
    uint4 o;
    o.x = (unsigned)f2bf(v0.x*scale) | ((unsigned)f2bf(v0.y*scale) << 16);
    o.y = (unsigned)f2bf(v0.z*scale) | ((unsigned)f2bf(v0.w*scale) << 16);
    o.z = (unsigned)f2bf(v1.x*scale) | ((unsigned)f2bf(v1.y*scale) << 16);
    o.w = (unsigned)f2bf(v1.z*scale) | ((unsigned)f2bf(v1.w*scale) << 16);
    *((uint4*)(dst + (size_t)row * D_N + lane * 8)) = o;
}

__device__ __forceinline__ void g2lds16(const ushort_t* g, ushort_t* l) {
    __builtin_amdgcn_global_load_lds(
        (const __attribute__((address_space(1))) void*)g,
        (__attribute__((address_space(3))) void*)l, 16, 0, 0);
}

// 128x128 tile GEMM (both inputs row-major [rows][K], i.e. B^T form),
// BK=32, 4 waves in 2x2, each wave 4x4 of mfma_f32_16x16x32_bf16.
// Epilogue: e = exp(64*theta) masked at target col; per-row sums via
// shfl + LDS; one global atomicAdd per row per block.
__global__ void gemm_arcface_kernel(const ushort_t* __restrict__ A,
                                    const ushort_t* __restrict__ Bm,
                                    const int* __restrict__ y,
                                    float* __restrict__ rowsum,
                                    float* __restrict__ tgt) {
    __shared__ ushort_t sA[128 * 32];  // 8 KB
    __shared__ ushort_t sB[128 * 32];  // 8 KB
    __shared__ float rowacc[128];

    int t    = threadIdx.x;
    int lane = t & 63;
    int w    = t >> 6;
    int wr   = w >> 1, wc = w & 1;
    int rm0  = blockIdx.y * 128;
    int cn0  = blockIdx.x * 128;

    if (t < 128) rowacc[t] = 0.0f;

    floatx4 acc[4][4];
#pragma unroll
    for (int i = 0; i < 4; i++)
#pragma unroll
        for (int j = 0; j < 4; j++) acc[i][j] = (floatx4){0.f, 0.f, 0.f, 0.f};

    // staging: thread t covers tile element range [t*8, t*8+8); row = t/4,
    // col = (t%4)*8 within the [128][32] tile. LDS dst = lane-order contiguous.
    const ushort_t* gA0 = A  + (size_t)(rm0 + (t >> 2)) * D_N + (t & 3) * 8;
    const ushort_t* gB0 = Bm + (size_t)(cn0 + (t >> 2)) * D_N + (t & 3) * 8;

    int lq = lane >> 4;   // quad
    int lc = lane & 15;   // index within quad group
    int fragA_off = (wr * 64 + lc) * 32 + lq * 8;  // + tm*512
    int fragB_off = (wc * 64 + lc) * 32 + lq * 8;  // + tn*512

    for (int kk = 0; kk < D_N; kk += 32) {
        g2lds16(gA0 + kk,            sA + t * 8);
        g2lds16(gA0 + 64 * D_N + kk, sA + (t + 256) * 8);
        g2lds16(gB0 + kk,            sB + t * 8);
        g2lds16(gB0 + 64 * D_N + kk, sB + (t + 256) * 8);
        __syncthreads();  // drains vmcnt for the LDS-bound loads

        short8 af[4], bf[4];
#pragma unroll
        for (int tm = 0; tm < 4; tm++)
            af[tm] = *(const short8*)(sA + fragA_off + tm * 512);
#pragma unroll
        for (int tn = 0; tn < 4; tn++)
            bf[tn] = *(const short8*)(sB + fragB_off + tn * 512);
#pragma unroll
        for (int tm = 0; tm < 4; tm++)
#pragma unroll
            for (int tn = 0; tn < 4; tn++)
                acc[tm][tn] = __builtin_amdgcn_mfma_f32_16x16x32_bf16(
                    af[tm], bf[tn], acc[tm][tn], 0, 0, 0);
        __syncthreads();  // before next iter overwrites LDS
    }

    // Epilogue. C/D layout (verified m89): col = lane&15, row = lq*4 + reg.
#pragma unroll
    for (int tm = 0; tm < 4; tm++) {
#pragma unroll
        for (int r = 0; r < 4; r++) {
            int lrow = wr * 64 + tm * 16 + lq * 4 + r;
            int grow = rm0 + lrow;
            int yv   = y[grow];
            float esum = 0.0f;
#pragma unroll
            for (int tn = 0; tn < 4; tn++) {
                int gcol = cn0 + wc * 64 + tn * 16 + lc;
                float theta = acc[tm][tn][r];
                if (gcol == yv) {
                    tgt[grow] = theta;  // exactly one writer per row
                } else {
                    esum += __expf(S_SCALE * theta);
                }
            }
            // butterfly over the 16 col-lanes (bits 0..3 stay within quad)
#pragma unroll
            for (int off = 1; off < 16; off <<= 1) esum += __shfl_xor(esum, off);
            if (lc == 0) atomicAdd(&rowacc[lrow], esum);
        }
    }
    __syncthreads();
    if (t < 128) atomicAdd(&rowsum[rm0 + t], rowacc[t]);
}

__global__ void finalize_kernel(const float* __restrict__ rowsum,
                                const float* __restrict__ tgt,
                                float* __restrict__ out) {
    __shared__ float red[256];
    int t = threadIdx.x;
    float s = 0.0f;
    for (int r = t; r < B_N; r += 256) {
        float tv = tgt[r];
        tv = fminf(fmaxf(tv, -1.0f + EPS_C), 1.0f - EPS_C);
        float num = S_SCALE * cosf(acosf(tv) + MARGIN);
        float den = expf(num) + rowsum[r];
        s += num - logf(den);
    }
    red[t] = s;
    __syncthreads();
    for (int o = 128; o > 0; o >>= 1) {
        if (t < o) red[t] += red[t + o];
        __syncthreads();
    }
    if (t == 0) out[0] = -red[0] / (float)B_N;
}

extern "C" void kernel_launch(void* const* d_in, const int* in_sizes, int n_in,
                              void* d_out, int out_size, void* d_ws, size_t ws_size,
                              hipStream_t stream) {
    const float* x = (const float*)d_in[0];
    const int*   y = (const int*)d_in[1];
    const float* W = (const float*)d_in[2];
    float* out = (float*)d_out;

    char* ws = (char*)d_ws;
    ushort_t* xn = (ushort_t*)ws;                              // 512 KB
    ushort_t* Wn = (ushort_t*)(ws + 524288);                   // 62.5 MB
    float* rowsum = (float*)(ws + 524288 + (size_t)C_N * D_N * 2);
    float* tgt    = rowsum + B_N;

    hipMemsetAsync(rowsum, 0, B_N * sizeof(float), stream);
    norm_rows_kernel<<<B_N / 4, 256, 0, stream>>>(x, xn, B_N);
    norm_rows_kernel<<<C_N / 4, 256, 0, stream>>>(W, Wn, C_N);
    dim3 grid(C_N / 128, B_N / 128);
    gemm_arcface_kernel<<<grid, 256, 0, stream>>>(xn, Wn, y, rowsum, tgt);
    finalize_kernel<<<1, 256, 0, stream>>>(rowsum, tgt, out);
}

// Round 2
// 256.001 us; speedup vs baseline: 1.0692x; 1.0692x over previous
//
#include <hip/hip_runtime.h>

// ArcFace loss, MI355X. B=512, D=512, C=64000, s=64, m=0.5.
// R2: double-buffered LDS GEMM + grid swizzle for Wn L2 sharing +
// fused prep kernel (norm x, norm W, zero rowsum) to cut launch count.

#define B_N 512
#define D_N 512
#define C_N 64000
#define S_SCALE 64.0f
#define MARGIN 0.5f
#define EPS_C 1e-7f

typedef unsigned short ushort_t;
typedef __attribute__((ext_vector_type(8))) short short8;   // 8 bf16 (4 VGPRs)
typedef __attribute__((ext_vector_type(4))) float floatx4;  // MFMA acc

__device__ __forceinline__ ushort_t f2bf(float f) {
    unsigned int u = __float_as_uint(f);
    u += 0x7fffu + ((u >> 16) & 1u);  // round-to-nearest-even
    return (ushort_t)(u >> 16);
}

// Fused prep: blocks [0,16000) normalize W rows (4 rows/block, 1 wave/row);
// blocks [16000,16128) normalize x rows; block 16128 zeroes rowsum.
// Loads: lane reads p[lane] and p[lane+64] -- two contiguous 1 KB segments.
__global__ void prep_kernel(const float* __restrict__ W,
                            const float* __restrict__ x,
                            ushort_t* __restrict__ Wn,
                            ushort_t* __restrict__ xn,
                            float* __restrict__ rowsum) {
    int b = blockIdx.x;
    int t = threadIdx.x;
    if (b == 16128) {
        rowsum[t] = 0.0f;
        rowsum[t + 256] = 0.0f;
        return;
    }
    const float* src;
    ushort_t* dst;
    int row;
    if (b < 16000) {
        row = b * 4 + (t >> 6);
        src = W + (size_t)row * D_N;
        dst = Wn + (size_t)row * D_N;
    } else {
        row = (b - 16000) * 4 + (t >> 6);
        src = x + (size_t)row * D_N;
        dst = xn + (size_t)row * D_N;
    }
    int lane = t & 63;
    const float4* p = (const float4*)src;
    float4 v0 = p[lane];        // elements [lane*4 .. lane*4+3]
    float4 v1 = p[lane + 64];   // elements [256+lane*4 ..]
    float ss = v0.x*v0.x + v0.y*v0.y + v0.z*v0.z + v0.w*v0.w
             + v1.x*v1.x + v1.y*v1.y + v1.z*v1.z + v1.w*v1.w;
#pragma unroll
    for (int off = 32; off > 0; off >>= 1) ss += __shfl_xor(ss, off);
    float sc = 1.0f / fmaxf(sqrtf(ss), 1e-12f);
    uint2 o0, o1;
    o0.x = (unsigned)f2bf(v0.x*sc) | ((unsigned)f2bf(v0.y*sc) << 16);
    o0.y = (unsigned)f2bf(v0.z*sc) | ((unsigned)f2bf(v0.w*sc) << 16);
    o1.x = (unsigned)f2bf(v1.x*sc) | ((unsigned)f2bf(v1.y*sc) << 16);
    o1.y = (unsigned)f2bf(v1.z*sc) | ((unsigned)f2bf(v1.w*sc) << 16);
    *(uint2*)(dst + lane * 4)       = o0;
    *(uint2*)(dst + 256 + lane * 4) = o1;
}

__device__ __forceinline__ void g2lds16(const ushort_t* g, ushort_t* l) {
    __builtin_amdgcn_global_load_lds(
        (const __attribute__((address_space(1))) void*)g,
        (__attribute__((address_space(3))) void*)l, 16, 0, 0);
}

// 128x128 tile, BK=32, double-buffered LDS: prefetch tile k+1 before
// computing tile k, so compute overlaps the global->LDS latency that the
// barrier's vmcnt(0) drain would otherwise fully expose (all blocks run
// in lockstep at this grid size -- no cross-block diversity to lean on).
// grid(4, 500): blockIdx.x = row-block (fast) so the 4 blocks sharing a
// Wn tile are dispatch-adjacent (L2/L3 co-fetch).
__global__ void gemm_arcface_kernel(const ushort_t* __restrict__ A,
                                    const ushort_t* __restrict__ Bm,
                                    const int* __restrict__ y,
                                    float* __restrict__ rowsum,
                                    float* __restrict__ tgt) {
    __shared__ ushort_t sA[2 * 128 * 32];  // 16 KB (2 buffers)
    __shared__ ushort_t sB[2 * 128 * 32];  // 16 KB
    __shared__ float rowacc[128];

    int t    = threadIdx.x;
    int lane = t & 63;
    int w    = t >> 6;
    int wr   = w >> 1, wc = w & 1;
    int rm0  = blockIdx.x * 128;   // row-block fast
    int cn0  = blockIdx.y * 128;   // col-block

    if (t < 128) rowacc[t] = 0.0f;

    floatx4 acc[4][4];
#pragma unroll
    for (int i = 0; i < 4; i++)
#pragma unroll
        for (int j = 0; j < 4; j++) acc[i][j] = (floatx4){0.f, 0.f, 0.f, 0.f};

    const ushort_t* gA0 = A  + (size_t)(rm0 + (t >> 2)) * D_N + (t & 3) * 8;
    const ushort_t* gB0 = Bm + (size_t)(cn0 + (t >> 2)) * D_N + (t & 3) * 8;

    int lq = lane >> 4;
    int lc = lane & 15;
    int fragA_off = (wr * 64 + lc) * 32 + lq * 8;  // + tm*512 + buf*4096
    int fragB_off = (wc * 64 + lc) * 32 + lq * 8;  // + tn*512 + buf*4096

    // prologue: stage tile 0 into buffer 0
    g2lds16(gA0,            sA + t * 8);
    g2lds16(gA0 + 64 * D_N, sA + (t + 256) * 8);
    g2lds16(gB0,            sB + t * 8);
    g2lds16(gB0 + 64 * D_N, sB + (t + 256) * 8);
    __syncthreads();

    for (int k = 0; k < 16; ++k) {
        int cur = (k & 1) * 4096;
        if (k < 15) {
            int nxt = ((k + 1) & 1) * 4096;
            int kk  = (k + 1) * 32;
            g2lds16(gA0 + kk,            sA + nxt + t * 8);
            g2lds16(gA0 + 64 * D_N + kk, sA + nxt + (t + 256) * 8);
            g2lds16(gB0 + kk,            sB + nxt + t * 8);
            g2lds16(gB0 + 64 * D_N + kk, sB + nxt + (t + 256) * 8);
        }

        short8 af[4], bf[4];
#pragma unroll
        for (int tm = 0; tm < 4; tm++)
            af[tm] = *(const short8*)(sA + cur + fragA_off + tm * 512);
#pragma unroll
        for (int tn = 0; tn < 4; tn++)
            bf[tn] = *(const short8*)(sB + cur + fragB_off + tn * 512);
#pragma unroll
        for (int tm = 0; tm < 4; tm++)
#pragma unroll
            for (int tn = 0; tn < 4; tn++)
                acc[tm][tn] = __builtin_amdgcn_mfma_f32_16x16x32_bf16(
                    af[tm], bf[tn], acc[tm][tn], 0, 0, 0);
        // one barrier per iter: drains the k+1 prefetch (had compute-time
        // to progress) and releases buffer cur for iter k+1's prefetch.
        __syncthreads();
    }

    // Epilogue. C/D layout: col = lane&15, row = lq*4 + reg (m89-verified).
#pragma unroll
    for (int tm = 0; tm < 4; tm++) {
#pragma unroll
        for (int r = 0; r < 4; r++) {
            int lrow = wr * 64 + tm * 16 + lq * 4 + r;
            int grow = rm0 + lrow;
            int yv   = y[grow];
            float esum = 0.0f;
#pragma unroll
            for (int tn = 0; tn < 4; tn++) {
                int gcol = cn0 + wc * 64 + tn * 16 + lc;
                float theta = acc[tm][tn][r];
                if (gcol == yv) {
                    tgt[grow] = theta;  // exactly one writer per row
                } else {
                    esum += __expf(S_SCALE * theta);
                }
            }
#pragma unroll
            for (int off = 1; off < 16; off <<= 1) esum += __shfl_xor(esum, off);
            if (lc == 0) atomicAdd(&rowacc[lrow], esum);
        }
    }
    __syncthreads();
    if (t < 128) atomicAdd(&rowsum[rm0 + t], rowacc[t]);
}

__global__ void finalize_kernel(const float* __restrict__ rowsum,
                                const float* __restrict__ tgt,
                                float* __restrict__ out) {
    __shared__ float red[256];
    int t = threadIdx.x;
    float s = 0.0f;
    for (int r = t; r < B_N; r += 256) {
        float tv = tgt[r];
        tv = fminf(fmaxf(tv, -1.0f + EPS_C), 1.0f - EPS_C);
        float num = S_SCALE * cosf(acosf(tv) + MARGIN);
        float den = expf(num) + rowsum[r];
        s += num - logf(den);
    }
    red[t] = s;
    __syncthreads();
    for (int o = 128; o > 0; o >>= 1) {
        if (t < o) red[t] += red[t + o];
        __syncthreads();
    }
    if (t == 0) out[0] = -red[0] / (float)B_N;
}

extern "C" void kernel_launch(void* const* d_in, const int* in_sizes, int n_in,
                              void* d_out, int out_size, void* d_ws, size_t ws_size,
                              hipStream_t stream) {
    const float* x = (const float*)d_in[0];
    const int*   y = (const int*)d_in[1];
    const float* W = (const float*)d_in[2];
    float* out = (float*)d_out;

    char* ws = (char*)d_ws;
    ushort_t* xn = (ushort_t*)ws;                              // 512 KB
    ushort_t* Wn = (ushort_t*)(ws + 524288);                   // 62.5 MB
    float* rowsum = (float*)(ws + 524288 + (size_t)C_N * D_N * 2);
    float* tgt    = rowsum + B_N;

    prep_kernel<<<16129, 256, 0, stream>>>(W, x, Wn, xn, rowsum);
    dim3 grid(4, C_N / 128);   // row-block fast -> Wn-tile sharers adjacent
    gemm_arcface_kernel<<<grid, 256, 0, stream>>>(xn, Wn, y, rowsum, tgt);
    finalize_kernel<<<1, 256, 0, stream>>>(rowsum, tgt, out);
}